// Round 7
// baseline (71.105 us; speedup 1.0000x reference)
//
#include <hip/hip_runtime.h>
#include <math.h>

// QuantumLayer: 4 qubits, 2 layers, B=524288.
//
// z_q = P^T C_q Q ; P/Q = 10 unordered pair-products of the two 4-dim real
// product-state factors (qubits 0,1 / 2,3). C = batch-uniform 4x10x10 tensor
// from the weights, packed float4 C4c[pi*10+qi] = {C0,C1,C2,C3}.
//
// Structure locked by rounds 1-6 evidence:
//  - two kernels (fusing the serial C-build into the wide kernel: R3, -49 us)
//  - 1 sample/thread, scalar v_fmac chains (packed f32x2 forms lost: R4/R5)
//  - [pi][qi][4] float4 layout so 4 coefficient loads merge into one 16B
//    load (R6: -3.2 us vs R2's 400 scalar loads)
//  - R7 delta (only change): C lives in a __constant__ symbol ->
//    addrspace(4) -> guaranteed s_load_dwordx4 / SGPR operands, ruling out
//    the per-lane global_load fallback (100 VMEM/thread + 210 MB L2).
//    build_C4 writes it via hipGetSymbolAddress (host query, capture-safe).

#define HALF_PI_F 1.57079632679489661923f

__constant__ float4 C4c[100];   // [pi][qi] -> {C0,C1,C2,C3}

__global__ __launch_bounds__(256) void build_C4(
    const float* __restrict__ weight,
    float4* __restrict__ C4g)  // = device address of C4c
{
    __shared__ float cw[16], sw[16];
    __shared__ float Ur[16][16], Ui[16][16];
    __shared__ float A[4][16][16];

    const int tid = threadIdx.x;
    if (tid < 16) {
        float h = 0.5f * weight[tid];
        __sincosf(h, &sw[tid], &cw[tid]);
    }
    __syncthreads();

    if (tid < 16) {
        const int col = tid;
        float re[16], im[16];
        #pragma unroll
        for (int i = 0; i < 16; ++i) { re[i] = 0.f; im[i] = 0.f; }
        re[col] = 1.f;

        #pragma unroll
        for (int layer = 0; layer < 2; ++layer) {
            #pragma unroll
            for (int q = 0; q < 4; ++q) {
                float cy = cw[layer*8 + q*2 + 0];
                float sy = sw[layer*8 + q*2 + 0];
                float cz = cw[layer*8 + q*2 + 1];
                float sz = sw[layer*8 + q*2 + 1];
                int st = 8 >> q;
                #pragma unroll
                for (int i = 0; i < 16; ++i) {
                    if (i & st) continue;
                    int j = i | st;
                    float r0 = re[i], r1 = re[j], i0 = im[i], i1 = im[j];
                    float nr0 = cy*r0 - sy*r1;
                    float nr1 = sy*r0 + cy*r1;
                    float ni0 = cy*i0 - sy*i1;
                    float ni1 = sy*i0 + cy*i1;
                    re[i] = nr0*cz + ni0*sz;
                    im[i] = ni0*cz - nr0*sz;
                    re[j] = nr1*cz - ni1*sz;
                    im[j] = ni1*cz + nr1*sz;
                }
            }
            #pragma unroll
            for (int q = 0; q < 4; ++q) {
                int cb = 8 >> q;
                int tb = 8 >> ((q + 1) & 3);
                #pragma unroll
                for (int i = 0; i < 16; ++i) {
                    if ((i & cb) && !(i & tb)) {
                        int j = i | tb;
                        float tr = re[i]; re[i] = re[j]; re[j] = tr;
                        float ti = im[i]; im[i] = im[j]; im[j] = ti;
                    }
                }
            }
        }
        #pragma unroll
        for (int i = 0; i < 16; ++i) { Ur[i][col] = re[i]; Ui[i][col] = im[i]; }
    }
    __syncthreads();

    for (int e = tid; e < 1024; e += 256) {
        int q = e >> 8, j = (e >> 4) & 15, k = e & 15;
        float sum = 0.f;
        for (int i = 0; i < 16; ++i) {
            float t = Ur[i][j]*Ur[i][k] + Ui[i][j]*Ui[i][k];
            sum += (i & (8 >> q)) ? -t : t;
        }
        A[q][j][k] = sum;
    }
    __syncthreads();

    if (tid < 100) {
        const int pu[10] = {0,0,0,0,1,1,1,2,2,3};
        const int pv[10] = {0,1,2,3,1,2,3,2,3,3};
        int pi = tid / 10, qi = tid % 10;
        int u = pu[pi], v = pv[pi], r = pu[qi], sI = pv[qi];
        int a1s[2] = {u, v}, a2s[2] = {v, u};
        int b1s[2] = {r, sI}, b2s[2] = {sI, r};
        int na = (u == v) ? 1 : 2;
        int nb = (r == sI) ? 1 : 2;
        float acc[4] = {0.f, 0.f, 0.f, 0.f};
        for (int ia = 0; ia < na; ++ia)
            for (int ib = 0; ib < nb; ++ib) {
                int j = a1s[ia]*4 + b1s[ib];
                int k = a2s[ia]*4 + b2s[ib];
                #pragma unroll
                for (int q = 0; q < 4; ++q) acc[q] += A[q][j][k];
            }
        C4g[tid] = float4{acc[0], acc[1], acc[2], acc[3]};
    }
}

__global__ __launch_bounds__(256) void qmain(
    const float* __restrict__ x,
    float* __restrict__ out,
    int B)
{
    const int s0 = blockIdx.x * 256 + threadIdx.x;

    float4 xv = (s0 < B) ? reinterpret_cast<const float4*>(x)[s0]
                         : float4{0.f, 0.f, 0.f, 0.f};

    const int pu[10] = {0,0,0,0,1,1,1,2,2,3};
    const int pv[10] = {0,1,2,3,1,2,3,2,3,3};

    float P[10], Q[10];
    {
        float xs[4] = {xv.x, xv.y, xv.z, xv.w};
        float c[4], s[4];
        #pragma unroll
        for (int q = 0; q < 4; ++q) {
            // tanh(x) = 1 - 2/(e^{2x}+1); fast-math err ~1e-6 vs 2e-2 threshold
            float e = __expf(2.f * xs[q]);
            float t = 1.f - __fdividef(2.f, e + 1.f);
            __sincosf(t * HALF_PI_F, &s[q], &c[q]);
        }
        float a4[4] = {c[0]*c[1], c[0]*s[1], s[0]*c[1], s[0]*s[1]};
        float b4[4] = {c[2]*c[3], c[2]*s[3], s[2]*c[3], s[2]*s[3]};
        #pragma unroll
        for (int i2 = 0; i2 < 10; ++i2) {
            P[i2] = a4[pu[i2]] * a4[pv[i2]];
            Q[i2] = b4[pu[i2]] * b4[pv[i2]];
        }
    }

    // z_q = sum_pi P[pi] * (sum_qi C4c[pi][qi][q] * Q[qi]); coefficients are
    // constant-AS (addrspace 4) with literal indices -> s_load_dwordx4, SGPR
    // operands to v_fmac_f32. No VMEM/LDS in the hot loop.
    float z0 = 0.f, z1 = 0.f, z2 = 0.f, z3 = 0.f;
    #pragma unroll
    for (int pi = 0; pi < 10; ++pi) {
        float t0 = 0.f, t1 = 0.f, t2 = 0.f, t3 = 0.f;
        #pragma unroll
        for (int qi = 0; qi < 10; ++qi) {
            float4 cv = C4c[pi*10 + qi];
            float qv = Q[qi];
            t0 = fmaf(cv.x, qv, t0);
            t1 = fmaf(cv.y, qv, t1);
            t2 = fmaf(cv.z, qv, t2);
            t3 = fmaf(cv.w, qv, t3);
        }
        float pvf = P[pi];
        z0 = fmaf(pvf, t0, z0);
        z1 = fmaf(pvf, t1, z1);
        z2 = fmaf(pvf, t2, z2);
        z3 = fmaf(pvf, t3, z3);
    }

    if (s0 < B)
        reinterpret_cast<float4*>(out)[s0] = float4{z0, z1, z2, z3};
}

extern "C" void kernel_launch(void* const* d_in, const int* in_sizes, int n_in,
                              void* d_out, int out_size, void* d_ws, size_t ws_size,
                              hipStream_t stream) {
    const float* x = (const float*)d_in[0];
    const float* w = (const float*)d_in[1];
    float* out = (float*)d_out;
    int B = in_sizes[0] / 4;

    // Device address of the __constant__ symbol; pure host-side query,
    // no stream work -> graph-capture safe. Cross-dispatch visibility is the
    // same L2-writeback-at-dispatch-boundary path R2-R6 relied on.
    void* sym = nullptr;
    hipGetSymbolAddress(&sym, HIP_SYMBOL(C4c));

    build_C4<<<1, 256, 0, stream>>>(w, (float4*)sym);
    int grid = (B + 255) / 256;  // 1 sample/thread, 256 threads/block
    qmain<<<grid, 256, 0, stream>>>(x, out, B);
}